// Round 6
// baseline (485.377 us; speedup 1.0000x reference)
//
#include <hip/hip_runtime.h>
#include <math.h>

#define D_DIM   256
#define N_ROWS  16384
#define K_CODES 8192
#define BM      128
#define BN      128
#define DKC     64
#define KCHUNK  1024
#define NCHUNK  (K_CODES / KCHUNK)   // 8

typedef __attribute__((ext_vector_type(8))) short s8v;           // 8 bf16 (A/B frag)
typedef __attribute__((ext_vector_type(4))) float f4v;           // 4 f32  (C/D frag)
typedef __attribute__((ext_vector_type(4))) unsigned short us4;  // 4 bf16 (8B write)
typedef unsigned long long u64;
typedef unsigned int u32;

// out layout: [0, 4194304) z_q_st | [4194304, 4210688) indices (as float) | [4210688] vq_loss
#define IDX_OFF  ((size_t)N_ROWS * D_DIM)
#define LOSS_OFF (IDX_OFF + N_ROWS)

// ws layout:
//   [0, 2MB)       u64 cand[N_ROWS][NCHUNK][2]
//   [2MB, +32KB)   float enorm[8192]
//   [2MB+32KB,+16K) float partials[4096]
//   [4MB, 12MB)    bf16 zh[16384][256]   (linear)
//   [12MB, 20MB)   bf16 zl[16384][256]   (linear)
//   [20MB, 24MB)   bf16 eh[8192][256]    (XOR-permuted per 128B block)
//   [24MB, 28MB)   bf16 el[8192][256]    (XOR-permuted per 128B block)
#define WS_ENORM_OFF    (2u * 1024u * 1024u)
#define WS_PARTIAL_OFF  (WS_ENORM_OFF + 32768u)
#define WS_ZH_OFF       (4u * 1024u * 1024u)
#define WS_ZL_OFF       (12u * 1024u * 1024u)
#define WS_EH_OFF       (20u * 1024u * 1024u)
#define WS_EL_OFF       (24u * 1024u * 1024u)
#define WS_NEED         (28u * 1024u * 1024u)

__device__ __forceinline__ unsigned short f2bf(float f) {   // fp32 -> bf16 RNE
    u32 u = __float_as_uint(f);
    return (unsigned short)((u + 0x7fffu + ((u >> 16) & 1u)) >> 16);
}
__device__ __forceinline__ float bf2f(unsigned short b) {
    return __uint_as_float(((u32)b) << 16);
}
__device__ __forceinline__ u32 f2ord(float f) {             // monotonic fp32 -> u32
    u32 u = __float_as_uint(f);
    return (u & 0x80000000u) ? ~u : (u | 0x80000000u);
}
__device__ __forceinline__ void gl2lds16(const void* g, void* l) {
    __builtin_amdgcn_global_load_lds(
        (const __attribute__((address_space(1))) unsigned int*)g,
        (__attribute__((address_space(3))) unsigned int*)l, 16, 0, 0);
}

// ---------------- pre-convert: z -> (zh, zl) linear planes ----------------
__global__ __launch_bounds__(256) void zconv_kernel(const float* __restrict__ z,
                                                    unsigned short* __restrict__ zh,
                                                    unsigned short* __restrict__ zl) {
    int q = blockIdx.x * 256 + threadIdx.x;       // 0 .. 1048575 (float4 index)
    float4 v = reinterpret_cast<const float4*>(z)[q];
    us4 h, lo;
    h[0] = f2bf(v.x); lo[0] = f2bf(v.x - bf2f(h[0]));
    h[1] = f2bf(v.y); lo[1] = f2bf(v.y - bf2f(h[1]));
    h[2] = f2bf(v.z); lo[2] = f2bf(v.z - bf2f(h[2]));
    h[3] = f2bf(v.w); lo[3] = f2bf(v.w - bf2f(h[3]));
    reinterpret_cast<us4*>(zh)[q] = h;
    reinterpret_cast<us4*>(zl)[q] = lo;
}

// ------- pre-convert: emb -> (eh, el) XOR-permuted planes + enorm (fused) -------
__global__ __launch_bounds__(256) void econv_kernel(const float* __restrict__ emb,
                                                    unsigned short* __restrict__ eh,
                                                    unsigned short* __restrict__ el,
                                                    float* __restrict__ enorm) {
    int row  = blockIdx.x * 4 + (threadIdx.x >> 6);
    int lane = threadIdx.x & 63;
    float4 v = reinterpret_cast<const float4*>(emb + (size_t)row * D_DIM)[lane];

    float s = v.x * v.x + v.y * v.y + v.z * v.z + v.w * v.w;
    #pragma unroll
    for (int off = 32; off >= 1; off >>= 1) s += __shfl_down(s, off);
    if (lane == 0) enorm[row] = s;

    us4 h, lo;
    h[0] = f2bf(v.x); lo[0] = f2bf(v.x - bf2f(h[0]));
    h[1] = f2bf(v.y); lo[1] = f2bf(v.y - bf2f(h[1]));
    h[2] = f2bf(v.z); lo[2] = f2bf(v.z - bf2f(h[2]));
    h[3] = f2bf(v.w); lo[3] = f2bf(v.w - bf2f(h[3]));
    // permuted position: XOR the 16B-chunk index (bits 4-6 of byte-in-128B-block) with (row&7)
    int ob = lane * 8;                                     // byte offset in 512B row
    int sb = (ob & ~127) | ((ob & 127) ^ ((row & 7) << 4));
    *reinterpret_cast<us4*>((char*)eh + (size_t)row * 512 + sb) = h;
    *reinterpret_cast<us4*>((char*)el + (size_t)row * 512 + sb) = lo;
}

// ---------------- MFMA argmin: top-2 per (row, chunk) ----------------
// A (z) frags direct from global planes; B (e) staged via global_load_lds
// from pre-permuted planes into linear LDS; reads apply the XOR (rule #21).
__global__ __launch_bounds__(256, 4) void argmin_kernel(const unsigned short* __restrict__ zh,
                                                        const unsigned short* __restrict__ zl,
                                                        const unsigned short* __restrict__ eh,
                                                        const unsigned short* __restrict__ el,
                                                        const float* __restrict__ enorm,
                                                        u64* __restrict__ cand) {
    __shared__ __align__(16) unsigned short esh[BN * DKC];   // 16KB
    __shared__ __align__(16) unsigned short esl[BN * DKC];   // 16KB

    const int tid = threadIdx.x;
    const int wv  = tid >> 6;          // wave 0..3 -> rows wv*32..+31
    const int l   = tid & 63;
    const int lr  = l & 15;            // A: row-in-frag / B: col-in-frag / D: col
    const int lg  = l >> 4;            // k-group; D: row-quad
    const int r0    = blockIdx.x * BM;
    const int cbase = blockIdx.y * KCHUNK;

    u64 t1[8], t2[8];                  // running top-2 key per owned row (i*4+r)
    #pragma unroll
    for (int q = 0; q < 8; ++q) { t1[q] = ~0ULL; t2[q] = ~0ULL; }

    // B-fragment LDS bases + swizzle masks (identical to verified round-5 read path)
    int brb[8], bsw[8];
    #pragma unroll
    for (int j = 0; j < 8; ++j) {
        int row = j * 16 + lr;
        brb[j] = row * 128; bsw[j] = (row & 7) << 4;
    }
    // A-fragment global row byte bases
    const char* zhp = (const char*)zh;
    const char* zlp = (const char*)zl;
    size_t arow[2];
    #pragma unroll
    for (int i = 0; i < 2; ++i)
        arow[i] = (size_t)(r0 + wv * 32 + i * 16 + lr) * 512;

    for (int ct = 0; ct < KCHUNK; ct += BN) {
        f4v acc[2][8];
        #pragma unroll
        for (int i = 0; i < 2; ++i)
            #pragma unroll
            for (int j = 0; j < 8; ++j)
                acc[i][j] = (f4v){0.f, 0.f, 0.f, 0.f};

        for (int d0b = 0; d0b < 512; d0b += 128) {          // byte offset of 128B k-block
            __syncthreads();                                // readers done with prev tile
            // stage B tiles: each wave fills its 4KB quarter of each plane
            #pragma unroll
            for (int n = 0; n < 4; ++n) {
                int lrow = wv * 32 + n * 8 + (l >> 3);      // row within 128-row tile
                size_t gsoff = (size_t)(cbase + ct + lrow) * 512 + d0b + (l & 7) * 16;
                gl2lds16((const char*)eh + gsoff, (char*)esh + (wv * 4 + n) * 1024);
                gl2lds16((const char*)el + gsoff, (char*)esl + (wv * 4 + n) * 1024);
            }
            // A fragments direct from global (L1-resident across ct reuse)
            s8v ah[2][2], al[2][2];                         // [kf][i]
            #pragma unroll
            for (int kf = 0; kf < 2; ++kf)
                #pragma unroll
                for (int i = 0; i < 2; ++i) {
                    size_t o = arow[i] + (size_t)d0b + kf * 64 + lg * 16;
                    ah[kf][i] = *reinterpret_cast<const s8v*>(zhp + o);
                    al[kf][i] = *reinterpret_cast<const s8v*>(zlp + o);
                }
            __syncthreads();                                // B tiles ready

            #pragma unroll
            for (int kf = 0; kf < 2; ++kf) {
                const int kb = kf * 64 + lg * 16;           // byte offset of lane's 8 bf16
                #pragma unroll
                for (int jh = 0; jh < 2; ++jh) {
                    s8v bh[4], bl[4];
                    #pragma unroll
                    for (int jj = 0; jj < 4; ++jj) {
                        int j = jh * 4 + jj;
                        int o = brb[j] + (kb ^ bsw[j]);
                        bh[jj] = *reinterpret_cast<const s8v*>(reinterpret_cast<const char*>(esh) + o);
                        bl[jj] = *reinterpret_cast<const s8v*>(reinterpret_cast<const char*>(esl) + o);
                    }
                    #pragma unroll
                    for (int i = 0; i < 2; ++i)
                        #pragma unroll
                        for (int jj = 0; jj < 4; ++jj) {
                            acc[i][jh * 4 + jj] = __builtin_amdgcn_mfma_f32_16x16x32_bf16(
                                ah[kf][i], bh[jj], acc[i][jh * 4 + jj], 0, 0, 0);
                            acc[i][jh * 4 + jj] = __builtin_amdgcn_mfma_f32_16x16x32_bf16(
                                ah[kf][i], bl[jj], acc[i][jh * 4 + jj], 0, 0, 0);
                            acc[i][jh * 4 + jj] = __builtin_amdgcn_mfma_f32_16x16x32_bf16(
                                al[kf][i], bh[jj], acc[i][jh * 4 + jj], 0, 0, 0);
                        }
                }
            }
        }

        // epilogue: dist = enorm[c] - 2*dot ; reduce over j, update per-row top-2
        float en[8];
        #pragma unroll
        for (int j = 0; j < 8; ++j) en[j] = enorm[cbase + ct + j * 16 + lr];

        #pragma unroll
        for (int i = 0; i < 2; ++i)
            #pragma unroll
            for (int r = 0; r < 4; ++r) {
                float m = fmaf(-2.f, acc[i][0][r], en[0]);
                int  mj = 0;
                #pragma unroll
                for (int j = 1; j < 8; ++j) {
                    float dj = fmaf(-2.f, acc[i][j][r], en[j]);
                    if (dj < m) { m = dj; mj = j; }
                }
                u32 c = (u32)(cbase + ct + mj * 16 + lr);
                u64 key = ((u64)f2ord(m) << 32) | c;
                int q = i * 4 + r;
                if (key < t1[q])      { t2[q] = t1[q]; t1[q] = key; }
                else if (key < t2[q]) { t2[q] = key; }
            }
    }

    // cross-lane top-2 merge within each 16-lane group, then write cand
    #pragma unroll
    for (int i = 0; i < 2; ++i)
        #pragma unroll
        for (int r = 0; r < 4; ++r) {
            int q = i * 4 + r;
            u64 a1 = t1[q], a2 = t2[q];
            #pragma unroll
            for (int mk = 1; mk <= 8; mk <<= 1) {
                u64 o1 = __shfl_xor(a1, mk);
                u64 o2 = __shfl_xor(a2, mk);
                u64 n1 = a1 < o1 ? a1 : o1;
                u64 hi = a1 < o1 ? o1 : a1;
                u64 m2 = a2 < o2 ? a2 : o2;
                a1 = n1;
                a2 = hi < m2 ? hi : m2;
            }
            if (lr == 0) {
                int row_g = r0 + wv * 32 + i * 16 + lg * 4 + r;
                u64* dst = &cand[((size_t)row_g * NCHUNK + blockIdx.y) * 2];
                dst[0] = a1; dst[1] = a2;
            }
        }
}

// ---------------- fallback (round-5 proven path, used if ws too small) ----------------
__global__ __launch_bounds__(256) void enorm_kernel(const float* __restrict__ emb,
                                                    float* __restrict__ enorm) {
    int row  = blockIdx.x * 4 + (threadIdx.x >> 6);
    int lane = threadIdx.x & 63;
    float4 v = reinterpret_cast<const float4*>(emb + (size_t)row * D_DIM)[lane];
    float s = v.x * v.x + v.y * v.y + v.z * v.z + v.w * v.w;
    #pragma unroll
    for (int off = 32; off >= 1; off >>= 1) s += __shfl_down(s, off);
    if (lane == 0) enorm[row] = s;
}

__global__ __launch_bounds__(256, 2) void argmin_fb_kernel(const float* __restrict__ z,
                                                           const float* __restrict__ emb,
                                                           const float* __restrict__ enorm,
                                                           u64* __restrict__ cand) {
    __shared__ __align__(16) unsigned short zsh[BM * DKC];
    __shared__ __align__(16) unsigned short zsl[BM * DKC];
    __shared__ __align__(16) unsigned short esh[BN * DKC];
    __shared__ __align__(16) unsigned short esl[BN * DKC];

    const int tid = threadIdx.x;
    const int wv  = tid >> 6;
    const int l   = tid & 63;
    const int lr  = l & 15;
    const int lg  = l >> 4;
    const int r0    = blockIdx.x * BM;
    const int cbase = blockIdx.y * KCHUNK;

    u64 t1[8], t2[8];
    #pragma unroll
    for (int q = 0; q < 8; ++q) { t1[q] = ~0ULL; t2[q] = ~0ULL; }

    int arb[2], asw[2], brb[8], bsw[8];
    #pragma unroll
    for (int i = 0; i < 2; ++i) {
        int row = wv * 32 + i * 16 + lr;
        arb[i] = row * 128; asw[i] = (row & 7) << 4;
    }
    #pragma unroll
    for (int j = 0; j < 8; ++j) {
        int row = j * 16 + lr;
        brb[j] = row * 128; bsw[j] = (row & 7) << 4;
    }

    for (int ct = 0; ct < KCHUNK; ct += BN) {
        f4v acc[2][8];
        #pragma unroll
        for (int i = 0; i < 2; ++i)
            #pragma unroll
            for (int j = 0; j < 8; ++j)
                acc[i][j] = (f4v){0.f, 0.f, 0.f, 0.f};

        for (int d0 = 0; d0 < D_DIM; d0 += DKC) {
            __syncthreads();
            #pragma unroll
            for (int it = 0; it < 8; ++it) {
                int q   = tid + it * 256;
                int row = q >> 4;
                int f4  = q & 15;
                int wo  = row * 128 + ((f4 * 8) ^ ((row & 7) << 4));

                float4 vz = *reinterpret_cast<const float4*>(
                    &z[(size_t)(r0 + row) * D_DIM + d0 + f4 * 4]);
                us4 h, lo;
                h[0] = f2bf(vz.x); lo[0] = f2bf(vz.x - bf2f(h[0]));
                h[1] = f2bf(vz.y); lo[1] = f2bf(vz.y - bf2f(h[1]));
                h[2] = f2bf(vz.z); lo[2] = f2bf(vz.z - bf2f(h[2]));
                h[3] = f2bf(vz.w); lo[3] = f2bf(vz.w - bf2f(h[3]));
                *reinterpret_cast<us4*>(reinterpret_cast<char*>(zsh) + wo) = h;
                *reinterpret_cast<us4*>(reinterpret_cast<char*>(zsl) + wo) = lo;

                float4 ve = *reinterpret_cast<const float4*>(
                    &emb[(size_t)(cbase + ct + row) * D_DIM + d0 + f4 * 4]);
                h[0] = f2bf(ve.x); lo[0] = f2bf(ve.x - bf2f(h[0]));
                h[1] = f2bf(ve.y); lo[1] = f2bf(ve.y - bf2f(h[1]));
                h[2] = f2bf(ve.z); lo[2] = f2bf(ve.z - bf2f(h[2]));
                h[3] = f2bf(ve.w); lo[3] = f2bf(ve.w - bf2f(h[3]));
                *reinterpret_cast<us4*>(reinterpret_cast<char*>(esh) + wo) = h;
                *reinterpret_cast<us4*>(reinterpret_cast<char*>(esl) + wo) = lo;
            }
            __syncthreads();

            #pragma unroll
            for (int kf = 0; kf < 2; ++kf) {
                const int kb = kf * 64 + lg * 16;
                s8v ah[2], al[2];
                #pragma unroll
                for (int i = 0; i < 2; ++i) {
                    int o = arb[i] + (kb ^ asw[i]);
                    ah[i] = *reinterpret_cast<const s8v*>(reinterpret_cast<const char*>(zsh) + o);
                    al[i] = *reinterpret_cast<const s8v*>(reinterpret_cast<const char*>(zsl) + o);
                }
                #pragma unroll
                for (int jh = 0; jh < 2; ++jh) {
                    s8v bh[4], bl[4];
                    #pragma unroll
                    for (int jj = 0; jj < 4; ++jj) {
                        int j = jh * 4 + jj;
                        int o = brb[j] + (kb ^ bsw[j]);
                        bh[jj] = *reinterpret_cast<const s8v*>(reinterpret_cast<const char*>(esh) + o);
                        bl[jj] = *reinterpret_cast<const s8v*>(reinterpret_cast<const char*>(esl) + o);
                    }
                    #pragma unroll
                    for (int i = 0; i < 2; ++i)
                        #pragma unroll
                        for (int jj = 0; jj < 4; ++jj) {
                            int j = jh * 4 + jj;
                            acc[i][j] = __builtin_amdgcn_mfma_f32_16x16x32_bf16(ah[i], bh[jj], acc[i][j], 0, 0, 0);
                            acc[i][j] = __builtin_amdgcn_mfma_f32_16x16x32_bf16(ah[i], bl[jj], acc[i][j], 0, 0, 0);
                            acc[i][j] = __builtin_amdgcn_mfma_f32_16x16x32_bf16(al[i], bh[jj], acc[i][j], 0, 0, 0);
                        }
                }
            }
        }

        float en[8];
        #pragma unroll
        for (int j = 0; j < 8; ++j) en[j] = enorm[cbase + ct + j * 16 + lr];

        #pragma unroll
        for (int i = 0; i < 2; ++i)
            #pragma unroll
            for (int r = 0; r < 4; ++r) {
                float m = fmaf(-2.f, acc[i][0][r], en[0]);
                int  mj = 0;
                #pragma unroll
                for (int j = 1; j < 8; ++j) {
                    float dj = fmaf(-2.f, acc[i][j][r], en[j]);
                    if (dj < m) { m = dj; mj = j; }
                }
                u32 c = (u32)(cbase + ct + mj * 16 + lr);
                u64 key = ((u64)f2ord(m) << 32) | c;
                int q = i * 4 + r;
                if (key < t1[q])      { t2[q] = t1[q]; t1[q] = key; }
                else if (key < t2[q]) { t2[q] = key; }
            }
    }

    #pragma unroll
    for (int i = 0; i < 2; ++i)
        #pragma unroll
        for (int r = 0; r < 4; ++r) {
            int q = i * 4 + r;
            u64 a1 = t1[q], a2 = t2[q];
            #pragma unroll
            for (int mk = 1; mk <= 8; mk <<= 1) {
                u64 o1 = __shfl_xor(a1, mk);
                u64 o2 = __shfl_xor(a2, mk);
                u64 n1 = a1 < o1 ? a1 : o1;
                u64 hi = a1 < o1 ? o1 : a1;
                u64 m2 = a2 < o2 ? a2 : o2;
                a1 = n1;
                a2 = hi < m2 ? hi : m2;
            }
            if (lr == 0) {
                int row_g = r0 + wv * 32 + i * 16 + lg * 4 + r;
                u64* dst = &cand[((size_t)row_g * NCHUNK + blockIdx.y) * 2];
                dst[0] = a1; dst[1] = a2;
            }
        }
}

// ---------------- exact fp32 rescore of 16 candidates + outputs ----------------
__global__ __launch_bounds__(256) void rescore_kernel(const float* __restrict__ z,
                                                      const float* __restrict__ emb,
                                                      const float* __restrict__ enorm,
                                                      const u64* __restrict__ cand,
                                                      float* __restrict__ out,
                                                      float* __restrict__ partials) {
    int row  = blockIdx.x * 4 + (threadIdx.x >> 6);
    int lane = threadIdx.x & 63;
    float4 zv = reinterpret_cast<const float4*>(z)[(size_t)row * 64 + lane];

    u64 best = ~0ULL;
    for (int s = 0; s < 2 * NCHUNK; ++s) {
        u32 c = ((u32)cand[(size_t)row * (2 * NCHUNK) + s]) & (K_CODES - 1);
        float4 ev = reinterpret_cast<const float4*>(emb)[(size_t)c * 64 + lane];
        float p = zv.x * ev.x + zv.y * ev.y + zv.z * ev.z + zv.w * ev.w;
        #pragma unroll
        for (int mk = 1; mk < 64; mk <<= 1) p += __shfl_xor(p, mk);
        float dist = fmaf(-2.f, p, enorm[c]);
        u64 key = ((u64)f2ord(dist) << 32) | c;
        best = key < best ? key : best;
    }
    u32 idx = ((u32)best) & (K_CODES - 1);
    if (lane == 0) out[IDX_OFF + row] = (float)idx;

    float4 ev = reinterpret_cast<const float4*>(emb)[(size_t)idx * 64 + lane];
    float tx = ev.x - zv.x, ty = ev.y - zv.y, tz = ev.z - zv.z, tw = ev.w - zv.w;
    float4 o;
    o.x = zv.x + tx; o.y = zv.y + ty; o.z = zv.z + tz; o.w = zv.w + tw;  // straight-through
    reinterpret_cast<float4*>(out)[(size_t)row * 64 + lane] = o;

    float s = tx * tx + ty * ty + tz * tz + tw * tw;
    #pragma unroll
    for (int off = 32; off >= 1; off >>= 1) s += __shfl_down(s, off);

    __shared__ float wsum[4];
    if (lane == 0) wsum[threadIdx.x >> 6] = s;
    __syncthreads();
    if (threadIdx.x == 0)
        partials[blockIdx.x] = (wsum[0] + wsum[1]) + (wsum[2] + wsum[3]);
}

__global__ __launch_bounds__(256) void loss_kernel(const float* __restrict__ partials,
                                                   float* __restrict__ out) {
    __shared__ float sm[256];
    float s = 0.0f;
    for (int i = threadIdx.x; i < 4096; i += 256) s += partials[i];
    sm[threadIdx.x] = s;
    __syncthreads();
    #pragma unroll
    for (int st = 128; st >= 1; st >>= 1) {
        if (threadIdx.x < st) sm[threadIdx.x] += sm[threadIdx.x + st];
        __syncthreads();
    }
    if (threadIdx.x == 0)
        out[LOSS_OFF] = sm[0] * (0.25f / (float)(N_ROWS * D_DIM));
}

extern "C" void kernel_launch(void* const* d_in, const int* in_sizes, int n_in,
                              void* d_out, int out_size, void* d_ws, size_t ws_size,
                              hipStream_t stream) {
    const float* z   = (const float*)d_in[0];
    const float* emb = (const float*)d_in[1];
    float* out = (float*)d_out;

    u64*   cand     = (u64*)d_ws;
    float* enorm    = (float*)((char*)d_ws + WS_ENORM_OFF);
    float* partials = (float*)((char*)d_ws + WS_PARTIAL_OFF);

    if (ws_size >= WS_NEED) {
        unsigned short* zh = (unsigned short*)((char*)d_ws + WS_ZH_OFF);
        unsigned short* zl = (unsigned short*)((char*)d_ws + WS_ZL_OFF);
        unsigned short* eh = (unsigned short*)((char*)d_ws + WS_EH_OFF);
        unsigned short* el = (unsigned short*)((char*)d_ws + WS_EL_OFF);
        zconv_kernel<<<(N_ROWS * D_DIM / 4) / 256, 256, 0, stream>>>(z, zh, zl);
        econv_kernel<<<K_CODES / 4, 256, 0, stream>>>(emb, eh, el, enorm);
        argmin_kernel<<<dim3(N_ROWS / BM, NCHUNK), 256, 0, stream>>>(zh, zl, eh, el, enorm, cand);
    } else {
        enorm_kernel<<<K_CODES / 4, 256, 0, stream>>>(emb, enorm);
        argmin_fb_kernel<<<dim3(N_ROWS / BM, NCHUNK), 256, 0, stream>>>(z, emb, enorm, cand);
    }
    rescore_kernel<<<N_ROWS / 4, 256, 0, stream>>>(z, emb, enorm, cand, out, partials);
    loss_kernel<<<1, 256, 0, stream>>>(partials, out);
}

// Round 7
// 351.724 us; speedup vs baseline: 1.3800x; 1.3800x over previous
//
#include <hip/hip_runtime.h>
#include <math.h>

#define D_DIM   256
#define N_ROWS  16384
#define K_CODES 8192
#define BM      128
#define BN      128
#define DKC     64
#define KCHUNK  1024
#define NCHUNK  (K_CODES / KCHUNK)   // 8

typedef __attribute__((ext_vector_type(8))) short s8v;           // 8 bf16 (A/B frag)
typedef __attribute__((ext_vector_type(4))) float f4v;           // 4 f32  (C/D frag)
typedef __attribute__((ext_vector_type(4))) unsigned short us4;  // 4 bf16 (8B write)
typedef unsigned long long u64;
typedef unsigned int u32;

// out layout: [0, 4194304) z_q_st | [4194304, 4210688) indices (as float) | [4210688] vq_loss
#define IDX_OFF  ((size_t)N_ROWS * D_DIM)
#define LOSS_OFF (IDX_OFF + N_ROWS)

// ws layout:
//   [0, 2MB)       u64 cand[N_ROWS][NCHUNK][2]
//   [2MB, +32KB)   float enorm[8192]
//   [2MB+32KB,+16K) float partials[4096]
//   [4MB, 12MB)    bf16 zh[16384][256]   (linear)
//   [12MB, 20MB)   bf16 zl[16384][256]   (linear)
//   [20MB, 24MB)   bf16 eh[8192][256]    (XOR-permuted per 128B block)
//   [24MB, 28MB)   bf16 el[8192][256]    (XOR-permuted per 128B block)
#define WS_ENORM_OFF    (2u * 1024u * 1024u)
#define WS_PARTIAL_OFF  (WS_ENORM_OFF + 32768u)
#define WS_ZH_OFF       (4u * 1024u * 1024u)
#define WS_ZL_OFF       (12u * 1024u * 1024u)
#define WS_EH_OFF       (20u * 1024u * 1024u)
#define WS_EL_OFF       (24u * 1024u * 1024u)
#define WS_NEED         (28u * 1024u * 1024u)

__device__ __forceinline__ unsigned short f2bf(float f) {   // fp32 -> bf16 RNE
    u32 u = __float_as_uint(f);
    return (unsigned short)((u + 0x7fffu + ((u >> 16) & 1u)) >> 16);
}
__device__ __forceinline__ float bf2f(unsigned short b) {
    return __uint_as_float(((u32)b) << 16);
}
__device__ __forceinline__ u32 f2ord(float f) {             // monotonic fp32 -> u32
    u32 u = __float_as_uint(f);
    return (u & 0x80000000u) ? ~u : (u | 0x80000000u);
}
__device__ __forceinline__ void gl2lds16(const void* g, void* l) {
    __builtin_amdgcn_global_load_lds(
        (const __attribute__((address_space(1))) unsigned int*)g,
        (__attribute__((address_space(3))) unsigned int*)l, 16, 0, 0);
}

// ---------------- pre-convert: z -> (zh, zl) linear planes ----------------
__global__ __launch_bounds__(256) void zconv_kernel(const float* __restrict__ z,
                                                    unsigned short* __restrict__ zh,
                                                    unsigned short* __restrict__ zl) {
    int q = blockIdx.x * 256 + threadIdx.x;       // 0 .. 1048575 (float4 index)
    float4 v = reinterpret_cast<const float4*>(z)[q];
    us4 h, lo;
    h[0] = f2bf(v.x); lo[0] = f2bf(v.x - bf2f(h[0]));
    h[1] = f2bf(v.y); lo[1] = f2bf(v.y - bf2f(h[1]));
    h[2] = f2bf(v.z); lo[2] = f2bf(v.z - bf2f(h[2]));
    h[3] = f2bf(v.w); lo[3] = f2bf(v.w - bf2f(h[3]));
    reinterpret_cast<us4*>(zh)[q] = h;
    reinterpret_cast<us4*>(zl)[q] = lo;
}

// ------- pre-convert: emb -> (eh, el) XOR-permuted planes + enorm (fused) -------
__global__ __launch_bounds__(256) void econv_kernel(const float* __restrict__ emb,
                                                    unsigned short* __restrict__ eh,
                                                    unsigned short* __restrict__ el,
                                                    float* __restrict__ enorm) {
    int row  = blockIdx.x * 4 + (threadIdx.x >> 6);
    int lane = threadIdx.x & 63;
    float4 v = reinterpret_cast<const float4*>(emb + (size_t)row * D_DIM)[lane];

    float s = v.x * v.x + v.y * v.y + v.z * v.z + v.w * v.w;
    #pragma unroll
    for (int off = 32; off >= 1; off >>= 1) s += __shfl_down(s, off);
    if (lane == 0) enorm[row] = s;

    us4 h, lo;
    h[0] = f2bf(v.x); lo[0] = f2bf(v.x - bf2f(h[0]));
    h[1] = f2bf(v.y); lo[1] = f2bf(v.y - bf2f(h[1]));
    h[2] = f2bf(v.z); lo[2] = f2bf(v.z - bf2f(h[2]));
    h[3] = f2bf(v.w); lo[3] = f2bf(v.w - bf2f(h[3]));
    // permuted position: XOR the 16B-chunk index (bits 4-6 of byte-in-128B-block) with (row&7)
    int ob = lane * 8;                                     // byte offset in 512B row
    int sb = (ob & ~127) | ((ob & 127) ^ ((row & 7) << 4));
    *reinterpret_cast<us4*>((char*)eh + (size_t)row * 512 + sb) = h;
    *reinterpret_cast<us4*>((char*)el + (size_t)row * 512 + sb) = lo;
}

// ---------------- MFMA argmin: top-2 per (row, chunk) ----------------
// A (z) frags direct from global planes; B (e) staged via global_load_lds
// from pre-permuted planes into linear LDS; reads apply the XOR (rule #21).
// launch_bounds (256,3): 170-VGPR cap. (256,4)'s 128 cap spilled ~650MB of
// scratch per dispatch (round-6 WRITE_SIZE) — do not tighten.
__global__ __launch_bounds__(256, 3) void argmin_kernel(const unsigned short* __restrict__ zh,
                                                        const unsigned short* __restrict__ zl,
                                                        const unsigned short* __restrict__ eh,
                                                        const unsigned short* __restrict__ el,
                                                        const float* __restrict__ enorm,
                                                        u64* __restrict__ cand) {
    __shared__ __align__(16) unsigned short esh[BN * DKC];   // 16KB
    __shared__ __align__(16) unsigned short esl[BN * DKC];   // 16KB

    const int tid = threadIdx.x;
    const int wv  = tid >> 6;          // wave 0..3 -> rows wv*32..+31
    const int l   = tid & 63;
    const int lr  = l & 15;            // A: row-in-frag / B: col-in-frag / D: col
    const int lg  = l >> 4;            // k-group; D: row-quad
    const int r0    = blockIdx.x * BM;
    const int cbase = blockIdx.y * KCHUNK;

    u64 t1[8], t2[8];                  // running top-2 key per owned row (i*4+r)
    #pragma unroll
    for (int q = 0; q < 8; ++q) { t1[q] = ~0ULL; t2[q] = ~0ULL; }

    // B-fragment LDS bases + swizzle masks (identical to verified round-5 read path)
    int brb[8], bsw[8];
    #pragma unroll
    for (int j = 0; j < 8; ++j) {
        int row = j * 16 + lr;
        brb[j] = row * 128; bsw[j] = (row & 7) << 4;
    }
    // A-fragment global row byte bases
    const char* zhp = (const char*)zh;
    const char* zlp = (const char*)zl;
    size_t arow[2];
    #pragma unroll
    for (int i = 0; i < 2; ++i)
        arow[i] = (size_t)(r0 + wv * 32 + i * 16 + lr) * 512;

    for (int ct = 0; ct < KCHUNK; ct += BN) {
        f4v acc[2][8];
        #pragma unroll
        for (int i = 0; i < 2; ++i)
            #pragma unroll
            for (int j = 0; j < 8; ++j)
                acc[i][j] = (f4v){0.f, 0.f, 0.f, 0.f};

        for (int d0b = 0; d0b < 512; d0b += 128) {          // byte offset of 128B k-block
            __syncthreads();                                // readers done with prev tile
            // stage B tiles: each wave fills its 4KB quarter of each plane
            #pragma unroll
            for (int n = 0; n < 4; ++n) {
                int lrow = wv * 32 + n * 8 + (l >> 3);      // row within 128-row tile
                size_t gsoff = (size_t)(cbase + ct + lrow) * 512 + d0b + (l & 7) * 16;
                gl2lds16((const char*)eh + gsoff, (char*)esh + (wv * 4 + n) * 1024);
                gl2lds16((const char*)el + gsoff, (char*)esl + (wv * 4 + n) * 1024);
            }
            __syncthreads();                                // B tiles ready

            #pragma unroll
            for (int kf = 0; kf < 2; ++kf) {
                const int kb = kf * 64 + lg * 16;           // byte offset of lane's 8 bf16
                // A fragments from global (L2-resident), loaded per-kf to cap live regs
                s8v ah[2], al[2];
                #pragma unroll
                for (int i = 0; i < 2; ++i) {
                    size_t o = arow[i] + (size_t)d0b + (size_t)kb;
                    ah[i] = *reinterpret_cast<const s8v*>(zhp + o);
                    al[i] = *reinterpret_cast<const s8v*>(zlp + o);
                }
                #pragma unroll
                for (int jh = 0; jh < 2; ++jh) {
                    s8v bh[4], bl[4];
                    #pragma unroll
                    for (int jj = 0; jj < 4; ++jj) {
                        int j = jh * 4 + jj;
                        int o = brb[j] + (kb ^ bsw[j]);
                        bh[jj] = *reinterpret_cast<const s8v*>(reinterpret_cast<const char*>(esh) + o);
                        bl[jj] = *reinterpret_cast<const s8v*>(reinterpret_cast<const char*>(esl) + o);
                    }
                    #pragma unroll
                    for (int i = 0; i < 2; ++i)
                        #pragma unroll
                        for (int jj = 0; jj < 4; ++jj) {
                            acc[i][jh * 4 + jj] = __builtin_amdgcn_mfma_f32_16x16x32_bf16(
                                ah[i], bh[jj], acc[i][jh * 4 + jj], 0, 0, 0);
                            acc[i][jh * 4 + jj] = __builtin_amdgcn_mfma_f32_16x16x32_bf16(
                                ah[i], bl[jj], acc[i][jh * 4 + jj], 0, 0, 0);
                            acc[i][jh * 4 + jj] = __builtin_amdgcn_mfma_f32_16x16x32_bf16(
                                al[i], bh[jj], acc[i][jh * 4 + jj], 0, 0, 0);
                        }
                }
            }
        }

        // epilogue: dist = enorm[c] - 2*dot ; reduce over j, update per-row top-2
        float en[8];
        #pragma unroll
        for (int j = 0; j < 8; ++j) en[j] = enorm[cbase + ct + j * 16 + lr];

        #pragma unroll
        for (int i = 0; i < 2; ++i)
            #pragma unroll
            for (int r = 0; r < 4; ++r) {
                float m = fmaf(-2.f, acc[i][0][r], en[0]);
                int  mj = 0;
                #pragma unroll
                for (int j = 1; j < 8; ++j) {
                    float dj = fmaf(-2.f, acc[i][j][r], en[j]);
                    if (dj < m) { m = dj; mj = j; }
                }
                u32 c = (u32)(cbase + ct + mj * 16 + lr);
                u64 key = ((u64)f2ord(m) << 32) | c;
                int q = i * 4 + r;
                if (key < t1[q])      { t2[q] = t1[q]; t1[q] = key; }
                else if (key < t2[q]) { t2[q] = key; }
            }
    }

    // cross-lane top-2 merge within each 16-lane group, then write cand
    #pragma unroll
    for (int i = 0; i < 2; ++i)
        #pragma unroll
        for (int r = 0; r < 4; ++r) {
            int q = i * 4 + r;
            u64 a1 = t1[q], a2 = t2[q];
            #pragma unroll
            for (int mk = 1; mk <= 8; mk <<= 1) {
                u64 o1 = __shfl_xor(a1, mk);
                u64 o2 = __shfl_xor(a2, mk);
                u64 n1 = a1 < o1 ? a1 : o1;
                u64 hi = a1 < o1 ? o1 : a1;
                u64 m2 = a2 < o2 ? a2 : o2;
                a1 = n1;
                a2 = hi < m2 ? hi : m2;
            }
            if (lr == 0) {
                int row_g = r0 + wv * 32 + i * 16 + lg * 4 + r;
                u64* dst = &cand[((size_t)row_g * NCHUNK + blockIdx.y) * 2];
                dst[0] = a1; dst[1] = a2;
            }
        }
}

// ---------------- fallback (round-5 proven path, used if ws too small) ----------------
__global__ __launch_bounds__(256) void enorm_kernel(const float* __restrict__ emb,
                                                    float* __restrict__ enorm) {
    int row  = blockIdx.x * 4 + (threadIdx.x >> 6);
    int lane = threadIdx.x & 63;
    float4 v = reinterpret_cast<const float4*>(emb + (size_t)row * D_DIM)[lane];
    float s = v.x * v.x + v.y * v.y + v.z * v.z + v.w * v.w;
    #pragma unroll
    for (int off = 32; off >= 1; off >>= 1) s += __shfl_down(s, off);
    if (lane == 0) enorm[row] = s;
}

__global__ __launch_bounds__(256, 2) void argmin_fb_kernel(const float* __restrict__ z,
                                                           const float* __restrict__ emb,
                                                           const float* __restrict__ enorm,
                                                           u64* __restrict__ cand) {
    __shared__ __align__(16) unsigned short zsh[BM * DKC];
    __shared__ __align__(16) unsigned short zsl[BM * DKC];
    __shared__ __align__(16) unsigned short esh[BN * DKC];
    __shared__ __align__(16) unsigned short esl[BN * DKC];

    const int tid = threadIdx.x;
    const int wv  = tid >> 6;
    const int l   = tid & 63;
    const int lr  = l & 15;
    const int lg  = l >> 4;
    const int r0    = blockIdx.x * BM;
    const int cbase = blockIdx.y * KCHUNK;

    u64 t1[8], t2[8];
    #pragma unroll
    for (int q = 0; q < 8; ++q) { t1[q] = ~0ULL; t2[q] = ~0ULL; }

    int arb[2], asw[2], brb[8], bsw[8];
    #pragma unroll
    for (int i = 0; i < 2; ++i) {
        int row = wv * 32 + i * 16 + lr;
        arb[i] = row * 128; asw[i] = (row & 7) << 4;
    }
    #pragma unroll
    for (int j = 0; j < 8; ++j) {
        int row = j * 16 + lr;
        brb[j] = row * 128; bsw[j] = (row & 7) << 4;
    }

    for (int ct = 0; ct < KCHUNK; ct += BN) {
        f4v acc[2][8];
        #pragma unroll
        for (int i = 0; i < 2; ++i)
            #pragma unroll
            for (int j = 0; j < 8; ++j)
                acc[i][j] = (f4v){0.f, 0.f, 0.f, 0.f};

        for (int d0 = 0; d0 < D_DIM; d0 += DKC) {
            __syncthreads();
            #pragma unroll
            for (int it = 0; it < 8; ++it) {
                int q   = tid + it * 256;
                int row = q >> 4;
                int f4  = q & 15;
                int wo  = row * 128 + ((f4 * 8) ^ ((row & 7) << 4));

                float4 vz = *reinterpret_cast<const float4*>(
                    &z[(size_t)(r0 + row) * D_DIM + d0 + f4 * 4]);
                us4 h, lo;
                h[0] = f2bf(vz.x); lo[0] = f2bf(vz.x - bf2f(h[0]));
                h[1] = f2bf(vz.y); lo[1] = f2bf(vz.y - bf2f(h[1]));
                h[2] = f2bf(vz.z); lo[2] = f2bf(vz.z - bf2f(h[2]));
                h[3] = f2bf(vz.w); lo[3] = f2bf(vz.w - bf2f(h[3]));
                *reinterpret_cast<us4*>(reinterpret_cast<char*>(zsh) + wo) = h;
                *reinterpret_cast<us4*>(reinterpret_cast<char*>(zsl) + wo) = lo;

                float4 ve = *reinterpret_cast<const float4*>(
                    &emb[(size_t)(cbase + ct + row) * D_DIM + d0 + f4 * 4]);
                h[0] = f2bf(ve.x); lo[0] = f2bf(ve.x - bf2f(h[0]));
                h[1] = f2bf(ve.y); lo[1] = f2bf(ve.y - bf2f(h[1]));
                h[2] = f2bf(ve.z); lo[2] = f2bf(ve.z - bf2f(h[2]));
                h[3] = f2bf(ve.w); lo[3] = f2bf(ve.w - bf2f(h[3]));
                *reinterpret_cast<us4*>(reinterpret_cast<char*>(esh) + wo) = h;
                *reinterpret_cast<us4*>(reinterpret_cast<char*>(esl) + wo) = lo;
            }
            __syncthreads();

            #pragma unroll
            for (int kf = 0; kf < 2; ++kf) {
                const int kb = kf * 64 + lg * 16;
                s8v ah[2], al[2];
                #pragma unroll
                for (int i = 0; i < 2; ++i) {
                    int o = arb[i] + (kb ^ asw[i]);
                    ah[i] = *reinterpret_cast<const s8v*>(reinterpret_cast<const char*>(zsh) + o);
                    al[i] = *reinterpret_cast<const s8v*>(reinterpret_cast<const char*>(zsl) + o);
                }
                #pragma unroll
                for (int jh = 0; jh < 2; ++jh) {
                    s8v bh[4], bl[4];
                    #pragma unroll
                    for (int jj = 0; jj < 4; ++jj) {
                        int j = jh * 4 + jj;
                        int o = brb[j] + (kb ^ bsw[j]);
                        bh[jj] = *reinterpret_cast<const s8v*>(reinterpret_cast<const char*>(esh) + o);
                        bl[jj] = *reinterpret_cast<const s8v*>(reinterpret_cast<const char*>(esl) + o);
                    }
                    #pragma unroll
                    for (int i = 0; i < 2; ++i)
                        #pragma unroll
                        for (int jj = 0; jj < 4; ++jj) {
                            int j = jh * 4 + jj;
                            acc[i][j] = __builtin_amdgcn_mfma_f32_16x16x32_bf16(ah[i], bh[jj], acc[i][j], 0, 0, 0);
                            acc[i][j] = __builtin_amdgcn_mfma_f32_16x16x32_bf16(ah[i], bl[jj], acc[i][j], 0, 0, 0);
                            acc[i][j] = __builtin_amdgcn_mfma_f32_16x16x32_bf16(al[i], bh[jj], acc[i][j], 0, 0, 0);
                        }
                }
            }
        }

        float en[8];
        #pragma unroll
        for (int j = 0; j < 8; ++j) en[j] = enorm[cbase + ct + j * 16 + lr];

        #pragma unroll
        for (int i = 0; i < 2; ++i)
            #pragma unroll
            for (int r = 0; r < 4; ++r) {
                float m = fmaf(-2.f, acc[i][0][r], en[0]);
                int  mj = 0;
                #pragma unroll
                for (int j = 1; j < 8; ++j) {
                    float dj = fmaf(-2.f, acc[i][j][r], en[j]);
                    if (dj < m) { m = dj; mj = j; }
                }
                u32 c = (u32)(cbase + ct + mj * 16 + lr);
                u64 key = ((u64)f2ord(m) << 32) | c;
                int q = i * 4 + r;
                if (key < t1[q])      { t2[q] = t1[q]; t1[q] = key; }
                else if (key < t2[q]) { t2[q] = key; }
            }
    }

    #pragma unroll
    for (int i = 0; i < 2; ++i)
        #pragma unroll
        for (int r = 0; r < 4; ++r) {
            int q = i * 4 + r;
            u64 a1 = t1[q], a2 = t2[q];
            #pragma unroll
            for (int mk = 1; mk <= 8; mk <<= 1) {
                u64 o1 = __shfl_xor(a1, mk);
                u64 o2 = __shfl_xor(a2, mk);
                u64 n1 = a1 < o1 ? a1 : o1;
                u64 hi = a1 < o1 ? o1 : a1;
                u64 m2 = a2 < o2 ? a2 : o2;
                a1 = n1;
                a2 = hi < m2 ? hi : m2;
            }
            if (lr == 0) {
                int row_g = r0 + wv * 32 + i * 16 + lg * 4 + r;
                u64* dst = &cand[((size_t)row_g * NCHUNK + blockIdx.y) * 2];
                dst[0] = a1; dst[1] = a2;
            }
        }
}

// ---------------- exact fp32 rescore of 16 candidates + outputs ----------------
__global__ __launch_bounds__(256) void rescore_kernel(const float* __restrict__ z,
                                                      const float* __restrict__ emb,
                                                      const float* __restrict__ enorm,
                                                      const u64* __restrict__ cand,
                                                      float* __restrict__ out,
                                                      float* __restrict__ partials) {
    int row  = blockIdx.x * 4 + (threadIdx.x >> 6);
    int lane = threadIdx.x & 63;
    float4 zv = reinterpret_cast<const float4*>(z)[(size_t)row * 64 + lane];

    u64 best = ~0ULL;
    for (int s = 0; s < 2 * NCHUNK; ++s) {
        u32 c = ((u32)cand[(size_t)row * (2 * NCHUNK) + s]) & (K_CODES - 1);
        float4 ev = reinterpret_cast<const float4*>(emb)[(size_t)c * 64 + lane];
        float p = zv.x * ev.x + zv.y * ev.y + zv.z * ev.z + zv.w * ev.w;
        #pragma unroll
        for (int mk = 1; mk < 64; mk <<= 1) p += __shfl_xor(p, mk);
        float dist = fmaf(-2.f, p, enorm[c]);
        u64 key = ((u64)f2ord(dist) << 32) | c;
        best = key < best ? key : best;
    }
    u32 idx = ((u32)best) & (K_CODES - 1);
    if (lane == 0) out[IDX_OFF + row] = (float)idx;

    float4 ev = reinterpret_cast<const float4*>(emb)[(size_t)idx * 64 + lane];
    float tx = ev.x - zv.x, ty = ev.y - zv.y, tz = ev.z - zv.z, tw = ev.w - zv.w;
    float4 o;
    o.x = zv.x + tx; o.y = zv.y + ty; o.z = zv.z + tz; o.w = zv.w + tw;  // straight-through
    reinterpret_cast<float4*>(out)[(size_t)row * 64 + lane] = o;

    float s = tx * tx + ty * ty + tz * tz + tw * tw;
    #pragma unroll
    for (int off = 32; off >= 1; off >>= 1) s += __shfl_down(s, off);

    __shared__ float wsum[4];
    if (lane == 0) wsum[threadIdx.x >> 6] = s;
    __syncthreads();
    if (threadIdx.x == 0)
        partials[blockIdx.x] = (wsum[0] + wsum[1]) + (wsum[2] + wsum[3]);
}

__global__ __launch_bounds__(256) void loss_kernel(const float* __restrict__ partials,
                                                   float* __restrict__ out) {
    __shared__ float sm[256];
    float s = 0.0f;
    for (int i = threadIdx.x; i < 4096; i += 256) s += partials[i];
    sm[threadIdx.x] = s;
    __syncthreads();
    #pragma unroll
    for (int st = 128; st >= 1; st >>= 1) {
        if (threadIdx.x < st) sm[threadIdx.x] += sm[threadIdx.x + st];
        __syncthreads();
    }
    if (threadIdx.x == 0)
        out[LOSS_OFF] = sm[0] * (0.25f / (float)(N_ROWS * D_DIM));
}

extern "C" void kernel_launch(void* const* d_in, const int* in_sizes, int n_in,
                              void* d_out, int out_size, void* d_ws, size_t ws_size,
                              hipStream_t stream) {
    const float* z   = (const float*)d_in[0];
    const float* emb = (const float*)d_in[1];
    float* out = (float*)d_out;

    u64*   cand     = (u64*)d_ws;
    float* enorm    = (float*)((char*)d_ws + WS_ENORM_OFF);
    float* partials = (float*)((char*)d_ws + WS_PARTIAL_OFF);

    if (ws_size >= WS_NEED) {
        unsigned short* zh = (unsigned short*)((char*)d_ws + WS_ZH_OFF);
        unsigned short* zl = (unsigned short*)((char*)d_ws + WS_ZL_OFF);
        unsigned short* eh = (unsigned short*)((char*)d_ws + WS_EH_OFF);
        unsigned short* el = (unsigned short*)((char*)d_ws + WS_EL_OFF);
        zconv_kernel<<<(N_ROWS * D_DIM / 4) / 256, 256, 0, stream>>>(z, zh, zl);
        econv_kernel<<<K_CODES / 4, 256, 0, stream>>>(emb, eh, el, enorm);
        argmin_kernel<<<dim3(N_ROWS / BM, NCHUNK), 256, 0, stream>>>(zh, zl, eh, el, enorm, cand);
    } else {
        enorm_kernel<<<K_CODES / 4, 256, 0, stream>>>(emb, enorm);
        argmin_fb_kernel<<<dim3(N_ROWS / BM, NCHUNK), 256, 0, stream>>>(z, emb, enorm, cand);
    }
    rescore_kernel<<<N_ROWS / 4, 256, 0, stream>>>(z, emb, enorm, cand, out, partials);
    loss_kernel<<<1, 256, 0, stream>>>(partials, out);
}